// Round 8
// baseline (200.012 us; speedup 1.0000x reference)
//
#include <hip/hip_runtime.h>

typedef __bf16 bf16;
typedef __bf16 bf16x2 __attribute__((ext_vector_type(2)));
typedef __bf16 bf16x4 __attribute__((ext_vector_type(4)));
typedef __bf16 bf16x8 __attribute__((ext_vector_type(8)));
typedef float f32x4 __attribute__((ext_vector_type(4)));

#define S_LEN 4096
#define DMODEL 512
#define NHEAD 8
#define DHEAD 64
#define BATCH 2
#define M_ROWS (BATCH * S_LEN)   // 8192
#define K_DIM 512
#define QLD 512                  // per-matrix leading dim after Q|K|V split

// ---------------------------------------------------------------------------
// async global->LDS, 16 B per lane (wave-uniform LDS base + 16*lane scatter).
// ---------------------------------------------------------------------------
__device__ __forceinline__ void async16(void* lds, const void* g) {
  __builtin_amdgcn_global_load_lds(
      (const __attribute__((address_space(1))) unsigned int*)g,
      (__attribute__((address_space(3))) unsigned int*)lds, 16, 0, 0);
}

// ---------------------------------------------------------------------------
// Per-wave dtype detection on x's first 4 KB: 1 if bf16, 0 if f32.
// ---------------------------------------------------------------------------
__device__ __forceinline__ int detect_bf16(const unsigned int* x, int lane) {
  int cnt = 0;
#pragma unroll
  for (int i = 0; i < 16; ++i) {
    const unsigned int w = x[lane * 16 + i];
    const unsigned int e = (w >> 7) & 0xFFu;
    cnt += (e >= 100u && e <= 140u) ? 1 : 0;
  }
#pragma unroll
  for (int off = 1; off < 64; off <<= 1) cnt += __shfl_xor(cnt, off);
  return (cnt >= 700) ? 1 : 0;
}

__device__ __forceinline__ bf16x8 ld8(const void* p, size_t e, bool asF32) {
  if (asF32) {
    const float* q = (const float*)p + e;
    const float4 a = *(const float4*)q;
    const float4 b = *(const float4*)(q + 4);
    bf16x8 r;
    r[0] = (bf16)a.x; r[1] = (bf16)a.y; r[2] = (bf16)a.z; r[3] = (bf16)a.w;
    r[4] = (bf16)b.x; r[5] = (bf16)b.y; r[6] = (bf16)b.z; r[7] = (bf16)b.w;
    return r;
  }
  return *(const bf16x8*)((const bf16*)p + e);
}

__device__ __forceinline__ float ld1(const void* p, size_t e, bool asF32) {
  return asF32 ? ((const float*)p)[e] : (float)((const bf16*)p)[e];
}

// ---------------------------------------------------------------------------
// One-shot conversion of x (2048 blocks) + all weights (768 blocks) to bf16.
// Self-detects dtype; block 0 publishes the flag for downstream kernels.
// ---------------------------------------------------------------------------
__global__ __launch_bounds__(256) void cvt_all(const void* __restrict__ x,
                                               const void* __restrict__ s0,
                                               const void* __restrict__ s1,
                                               const void* __restrict__ s2,
                                               const void* __restrict__ s3,
                                               bf16* __restrict__ xb,
                                               bf16* __restrict__ warena,
                                               int* __restrict__ flag) {
  const int isbf = detect_bf16((const unsigned int*)x, threadIdx.x & 63);
  const bool f32in = (isbf == 0);
  const int b = blockIdx.x;
  if (b == 0 && threadIdx.x == 0) *flag = isbf;
  if (b < 2048) {  // x: 8192*512 = 2048 * 2048 elems
    const size_t idx = ((size_t)b * 256 + threadIdx.x) * 8;
    *(bf16x8*)(xb + idx) = ld8(x, idx, f32in);
    return;
  }
  const int wb = b - 2048;
  const void* s;
  size_t doff;
  int lb;
  if (wb < 384)      { s = s0; doff = 0;        lb = wb; }
  else if (wb < 512) { s = s1; doff = 786432;   lb = wb - 384; }
  else if (wb < 640) { s = s2; doff = 1048576;  lb = wb - 512; }
  else               { s = s3; doff = 1310720;  lb = wb - 640; }
  const size_t idx = (size_t)lb * 2048 + threadIdx.x * 8;
  *(bf16x8*)(warena + doff + idx) = ld8(s, idx, f32in);
}

// ---------------------------------------------------------------------------
// QKV GEMM (R2-proven body): qkv = xb @ in_proj_w^T + b, [M=8192, N=1536].
// C-write splits into Q|K|V arrays (n>>9 selects; each 8192x512).
// ---------------------------------------------------------------------------
__global__ __launch_bounds__(256) void gemm_qkv(const bf16* __restrict__ A,
                                                const bf16* __restrict__ W,
                                                const void* __restrict__ bias,
                                                bf16* __restrict__ C,
                                                const int* __restrict__ flag) {
  __shared__ __align__(16) bf16 As[128 * 64];
  __shared__ __align__(16) bf16 Ws[128 * 64];

  const bool f32in = (*flag == 0);
  const int t = threadIdx.x;
  const int lane = t & 63;
  const int wave = t >> 6;
  const int wm = (wave >> 1) * 64;
  const int wn = (wave & 1) * 64;
  const int l16 = lane & 15;
  const int quad = lane >> 4;

  constexpr int NB = 1536 / 128;  // 12 n-blocks per m-band
  const int bid = blockIdx.x;
  const int xcd = bid & 7;
  const int r = bid >> 3;
  const int m0 = (xcd * 8 + r / NB) * 128;
  const int n0 = (r % NB) * 128;

  const int rr = lane >> 3;
  const int cb = (lane & 7) ^ rr;      // XOR swizzle (source side)
  const int sw = l16 & 7;              // read-side swizzle key

  f32x4 acc[4][4];
#pragma unroll
  for (int i = 0; i < 4; ++i)
#pragma unroll
    for (int j = 0; j < 4; ++j) acc[i][j] = (f32x4){0.f, 0.f, 0.f, 0.f};

  for (int kt = 0; kt < K_DIM; kt += 64) {
    __syncthreads();
#pragma unroll
    for (int i = 0; i < 4; ++i) {
      const int r0 = wave * 32 + i * 8;
      async16(&As[r0 * 64], &A[(size_t)(m0 + r0 + rr) * K_DIM + kt + cb * 8]);
    }
#pragma unroll
    for (int i = 0; i < 4; ++i) {
      const int r0 = wave * 32 + i * 8;
      async16(&Ws[r0 * 64], &W[(size_t)(n0 + r0 + rr) * K_DIM + kt + cb * 8]);
    }
    __syncthreads();
#pragma unroll
    for (int ks = 0; ks < 2; ++ks) {
      bf16x8 af[4], wf[4];
#pragma unroll
      for (int mt = 0; mt < 4; ++mt)
        af[mt] = *(const bf16x8*)&As[(wm + mt * 16 + l16) * 64 +
                                     (((ks * 4 + quad) ^ sw) * 8)];
#pragma unroll
      for (int nt = 0; nt < 4; ++nt)
        wf[nt] = *(const bf16x8*)&Ws[(wn + nt * 16 + l16) * 64 +
                                     (((ks * 4 + quad) ^ sw) * 8)];
#pragma unroll
      for (int mt = 0; mt < 4; ++mt)
#pragma unroll
        for (int nt = 0; nt < 4; ++nt)
          acc[mt][nt] = __builtin_amdgcn_mfma_f32_16x16x32_bf16(af[mt], wf[nt],
                                                                acc[mt][nt], 0, 0, 0);
    }
  }

#pragma unroll
  for (int nt = 0; nt < 4; ++nt) {
    const int n = n0 + wn + nt * 16 + l16;        // 0..1535
    const float bv = ld1(bias, n, f32in);
    bf16* Cm = C + (size_t)(n >> 9) * ((size_t)M_ROWS * DMODEL) + (n & 511);
#pragma unroll
    for (int mt = 0; mt < 4; ++mt) {
#pragma unroll
      for (int r4 = 0; r4 < 4; ++r4) {
        const int m = m0 + wm + mt * 16 + quad * 4 + r4;
        Cm[(size_t)m * DMODEL] = (bf16)(acc[mt][nt][r4] + bv);
      }
    }
  }
}

// ---------------------------------------------------------------------------
// Small GEMM, R16: 64x64 tile, grid 1024 = 4 blocks/CU (was 128x64 @ 512
// blocks = 2/CU, 25% occupancy -- the grid size itself was the occupancy
// limiter for these latency-bound dispatches). LDS 32 KB dbuf (4x32=128 <=
// 160), VGPR ~60, 16 waves/CU: double the latency-hiding pool.
// ---------------------------------------------------------------------------
template <bool RELU>
__global__ __launch_bounds__(256) void gemm_bt(const bf16* __restrict__ A,
                                               const bf16* __restrict__ W,
                                               const void* __restrict__ bias,
                                               bf16* __restrict__ C,
                                               const int* __restrict__ flag) {
  __shared__ __align__(16) bf16 As[2][64 * 64];
  __shared__ __align__(16) bf16 Ws[2][64 * 64];

  const bool f32in = (*flag == 0);
  const int t = threadIdx.x;
  const int lane = t & 63;
  const int wave = t >> 6;        // 0..3
  const int wm = wave * 16;
  const int l16 = lane & 15;
  const int quad = lane >> 4;

  constexpr int NB = 512 / 64;         // 8 n-blocks per m-band
  constexpr int MPX = (M_ROWS / 64) / 8;  // 16 m-bands per XCD
  const int bid = blockIdx.x;          // 0..1023
  const int xcd = bid & 7;
  const int r = bid >> 3;
  const int m0 = (xcd * MPX + r / NB) * 64;
  const int n0 = (r % NB) * 64;

  const int rr = lane >> 3;
  const int cb = (lane & 7) ^ rr;      // XOR swizzle (source side)
  const int sw = l16 & 7;              // read-side swizzle key

  f32x4 acc[4];
#pragma unroll
  for (int j = 0; j < 4; ++j) acc[j] = (f32x4){0.f, 0.f, 0.f, 0.f};

  auto stage = [&](int buf, int kt) {
#pragma unroll
    for (int i = 0; i < 2; ++i) {
      const int r0 = wave * 16 + i * 8;
      async16(&As[buf][r0 * 64],
              &A[(size_t)(m0 + r0 + rr) * K_DIM + kt + cb * 8]);
      async16(&Ws[buf][r0 * 64],
              &W[(size_t)(n0 + r0 + rr) * K_DIM + kt + cb * 8]);
    }
  };

  stage(0, 0);  // prologue
  constexpr int NIT = K_DIM / 64;
  for (int it = 0; it < NIT; ++it) {
    const int cur = it & 1;
    __syncthreads();  // drains tile `it` loads; fences buf[cur^1] reuse
    if (it + 1 < NIT) stage(cur ^ 1, (it + 1) * 64);
#pragma unroll
    for (int ks = 0; ks < 2; ++ks) {
      bf16x8 af, wf[4];
      af = *(const bf16x8*)&As[cur][(wm + l16) * 64 +
                                    (((ks * 4 + quad) ^ sw) * 8)];
#pragma unroll
      for (int nt = 0; nt < 4; ++nt)
        wf[nt] = *(const bf16x8*)&Ws[cur][(nt * 16 + l16) * 64 +
                                          (((ks * 4 + quad) ^ sw) * 8)];
#pragma unroll
      for (int nt = 0; nt < 4; ++nt)
        acc[nt] = __builtin_amdgcn_mfma_f32_16x16x32_bf16(af, wf[nt],
                                                          acc[nt], 0, 0, 0);
    }
  }

#pragma unroll
  for (int nt = 0; nt < 4; ++nt) {
    const int n = n0 + nt * 16 + l16;
    const float bv = ld1(bias, n, f32in);
#pragma unroll
    for (int r4 = 0; r4 < 4; ++r4) {
      const int m = m0 + wm + quad * 4 + r4;
      float v = acc[nt][r4] + bv;
      if (RELU) v = fmaxf(v, 0.f);
      C[(size_t)m * 512 + n] = (bf16)v;
    }
  }
}

// ---------------------------------------------------------------------------
// Sliding-window attention (R15-frozen: QBLK=128, 8 waves, K LDS dbuf via
// async16, V reg-prefetch transpose, exp2 softmax, setprio).
// ctx overwrites the block's OWN Q rows -> no cross-block hazard.
// ---------------------------------------------------------------------------
__global__ __launch_bounds__(512) void attn_fwd(bf16* __restrict__ qkv,
                                                const int* __restrict__ wptr) {
  __shared__ __align__(16) bf16 Kt[2][64 * 64];  // swizzled [key][dh]
  __shared__ __align__(16) bf16 Vt[2][64][72];   // [buf][dh][key] (+8 pad)
  __shared__ __align__(16) bf16 Pbuf[8][16][72]; // per-wave [q][key] (+8 pad)

  const bf16* Q = qkv;
  const bf16* K = qkv + (size_t)M_ROWS * DMODEL;
  const bf16* V = qkv + 2 * (size_t)M_ROWS * DMODEL;
  bf16* ctxw = qkv;  // ctx overwrites Q in place

  const int t = threadIdx.x;       // 0..511
  const int lane = t & 63;
  const int wave = t >> 6;         // 0..7
  const int l16 = lane & 15;
  const int quad = lane >> 4;
  const int rr = lane >> 3;
  const int cb = (lane & 7) ^ rr;   // K staging source swizzle
  const int sw = l16 & 7;           // K read swizzle key

  const int bid = blockIdx.x;               // 0..511
  const int xcd = bid & 7;
  const int jj = bid >> 3;                  // 0..63
  const int pair = xcd * 2 + (jj >> 5);     // 0..15 = (b,h)
  const int qblk = jj & 31;                 // 0..31
  const int h = pair & 7;
  const int b = pair >> 3;
  const int qbase = qblk * 128;
  int window = *wptr;
  if (window < 0) window = 0;
  if (window > S_LEN) window = S_LEN;
  const float sc_log2e = 0.125f * 1.44269504f;  // scale * log2(e)

  const int qrow = qbase + wave * 16 + l16;
  const bf16* qp = Q + (size_t)(b * S_LEN + qrow) * QLD + h * DHEAD;
  const bf16x8 qf0 = *(const bf16x8*)(qp + quad * 8);
  const bf16x8 qf1 = *(const bf16x8*)(qp + 32 + quad * 8);

  f32x4 o[4];
#pragma unroll
  for (int nt = 0; nt < 4; ++nt) o[nt] = (f32x4){0.f, 0.f, 0.f, 0.f};
  float lp[4] = {0.f, 0.f, 0.f, 0.f};

  int kstart = qbase - window;
  if (kstart < 0) kstart = 0;
  kstart &= ~63;
  int kend = qbase + 128 + window;
  if (kend > S_LEN) kend = S_LEN;
  const int niter = (kend - kstart + 63) >> 6;

  // V transpose mapping for 512 threads: 2 keys x 4 dh per thread.
  const int vk = (t & 31) * 2;        // key pair 0..62
  const int vd = (t >> 5) * 4;        // dh group 0..60
  const bf16* vbase = V + (size_t)(b * S_LEN) * QLD + h * DHEAD + vd;
  const bf16* kbase = K + (size_t)(b * S_LEN) * QLD + h * DHEAD;

  // prologue: stage K tile 0 into Kt[0] (1 async16/thread, 8 rows/wave)
  {
    const int r0 = wave * 8;
    async16(&Kt[0][r0 * 64],
            &kbase[(size_t)(kstart + r0 + rr) * QLD + cb * 8]);
  }
  {  // prologue: stage V tile 0 into Vt[0]
    const bf16* p = vbase + (size_t)(kstart + vk) * QLD;
    const bf16x4 va = *(const bf16x4*)p;
    const bf16x4 vb = *(const bf16x4*)(p + QLD);
#pragma unroll
    for (int j = 0; j < 4; ++j) {
      bf16x2 pr; pr[0] = va[j]; pr[1] = vb[j];
      *(bf16x2*)&Vt[0][vd + j][vk] = pr;
    }
  }

  for (int it = 0; it < niter; ++it) {
    const int kt = kstart + it * 64;
    const int cur = it & 1;
    __syncthreads();  // implicit vmcnt(0): Kt[cur] async loads complete

    bf16x4 na, nb;
    const bool have_next = (it + 1 < niter);
    if (have_next) {
      {
        const int r0 = wave * 8;
        async16(&Kt[cur ^ 1][r0 * 64],
                &kbase[(size_t)(kt + 64 + r0 + rr) * QLD + cb * 8]);
      }
      const bf16* p = vbase + (size_t)(kt + 64 + vk) * QLD;
      na = *(const bf16x4*)p;
      nb = *(const bf16x4*)(p + QLD);
    }

    f32x4 s[4];
#pragma unroll
    for (int t4 = 0; t4 < 4; ++t4) s[t4] = (f32x4){0.f, 0.f, 0.f, 0.f};

    __builtin_amdgcn_s_setprio(1);
#pragma unroll
    for (int t4 = 0; t4 < 4; ++t4) {
      const int row = t4 * 16 + l16;
      const bf16x8 k0 = *(const bf16x8*)&Kt[cur][row * 64 + ((quad ^ sw) * 8)];
      const bf16x8 k1 =
          *(const bf16x8*)&Kt[cur][row * 64 + (((4 + quad) ^ sw) * 8)];
      s[t4] = __builtin_amdgcn_mfma_f32_16x16x32_bf16(qf0, k0, s[t4], 0, 0, 0);
      s[t4] = __builtin_amdgcn_mfma_f32_16x16x32_bf16(qf1, k1, s[t4], 0, 0, 0);
    }
    __builtin_amdgcn_s_setprio(0);

#pragma unroll
    for (int r = 0; r < 4; ++r) {
      const int q = qbase + wave * 16 + quad * 4 + r;
      const int lo = q - window, hi = q + window;
#pragma unroll
      for (int t4 = 0; t4 < 4; ++t4) {
        const int key = kt + t4 * 16 + l16;
        const float p = (key >= lo && key <= hi)
                            ? __builtin_amdgcn_exp2f(s[t4][r] * sc_log2e)
                            : 0.f;
        lp[r] += p;
        Pbuf[wave][quad * 4 + r][t4 * 16 + l16] = (bf16)p;
      }
    }

    const bf16x8 pf0 = *(const bf16x8*)&Pbuf[wave][l16][quad * 8];
    const bf16x8 pf1 = *(const bf16x8*)&Pbuf[wave][l16][32 + quad * 8];
    __builtin_amdgcn_s_setprio(1);
#pragma unroll
    for (int nt = 0; nt < 4; ++nt) {
      const bf16x8 v0 = *(const bf16x8*)&Vt[cur][nt * 16 + l16][quad * 8];
      const bf16x8 v1 = *(const bf16x8*)&Vt[cur][nt * 16 + l16][32 + quad * 8];
      o[nt] = __builtin_amdgcn_mfma_f32_16x16x32_bf16(pf0, v0, o[nt], 0, 0, 0);
      o[nt] = __builtin_amdgcn_mfma_f32_16x16x32_bf16(pf1, v1, o[nt], 0, 0, 0);
    }
    __builtin_amdgcn_s_setprio(0);

    if (have_next) {
#pragma unroll
      for (int j = 0; j < 4; ++j) {
        bf16x2 pr; pr[0] = na[j]; pr[1] = nb[j];
        *(bf16x2*)&Vt[cur ^ 1][vd + j][vk] = pr;
      }
    }
  }

#pragma unroll
  for (int r = 0; r < 4; ++r) {
#pragma unroll
    for (int off = 1; off < 16; off <<= 1) lp[r] += __shfl_xor(lp[r], off);
    const float inv = (lp[r] > 0.f) ? (1.0f / lp[r]) : 0.f;
    const int q = qbase + wave * 16 + quad * 4 + r;
#pragma unroll
    for (int nt = 0; nt < 4; ++nt) {
      ctxw[(size_t)(b * S_LEN + q) * QLD + h * DHEAD + nt * 16 + l16] =
          (bf16)(o[nt][r] * inv);
    }
  }
}

// ---------------------------------------------------------------------------
// Fused residual + LayerNorm (R3-verified). One wave per row, 4 rows/block.
// ---------------------------------------------------------------------------
template <bool A_RAW, bool OUT_RAW>
__global__ __launch_bounds__(256) void ln_fused(const void* __restrict__ a,
                                                const bf16* __restrict__ bres,
                                                const void* __restrict__ g,
                                                const void* __restrict__ be,
                                                void* __restrict__ out,
                                                const int* __restrict__ flag) {
  const bool f32in = (*flag == 0);
  const int row = blockIdx.x * 4 + (threadIdx.x >> 6);
  const int lane = threadIdx.x & 63;
  const size_t base = (size_t)row * DMODEL + lane * 8;
  const bf16x8 va = ld8(a, base, A_RAW && f32in);
  const bf16x8 vb = *(const bf16x8*)(bres + base);
  float v[8], s = 0.f, s2 = 0.f;
#pragma unroll
  for (int j = 0; j < 8; ++j) {
    v[j] = (float)va[j] + (float)vb[j];
    s += v[j];
    s2 += v[j] * v[j];
  }
#pragma unroll
  for (int off = 1; off < 64; off <<= 1) {
    s += __shfl_xor(s, off);
    s2 += __shfl_xor(s2, off);
  }
  const float mean = s * (1.0f / DMODEL);
  float var = s2 * (1.0f / DMODEL) - mean * mean;
  if (var < 0.f) var = 0.f;
  const float rstd = rsqrtf(var + 1e-5f);
  const bf16x8 gv = ld8(g, lane * 8, f32in);
  const bf16x8 bev = ld8(be, lane * 8, f32in);
  float ov[8];
#pragma unroll
  for (int j = 0; j < 8; ++j)
    ov[j] = (v[j] - mean) * rstd * (float)gv[j] + (float)bev[j];
  if (OUT_RAW && f32in) {
    float4 o0 = {ov[0], ov[1], ov[2], ov[3]};
    float4 o1 = {ov[4], ov[5], ov[6], ov[7]};
    *(float4*)((float*)out + base) = o0;
    *(float4*)((float*)out + base + 4) = o1;
  } else {
    bf16x8 ob;
#pragma unroll
    for (int j = 0; j < 8; ++j) ob[j] = (bf16)ov[j];
    *(bf16x8*)((bf16*)out + base) = ob;
  }
}

// ---------------------------------------------------------------------------
extern "C" void kernel_launch(void* const* d_in, const int* in_sizes, int n_in,
                              void* d_out, int out_size, void* d_ws, size_t ws_size,
                              hipStream_t stream) {
  const void* x          = d_in[0];
  const void* in_proj_w  = d_in[1];
  const void* in_proj_b  = d_in[2];
  const void* out_proj_w = d_in[3];
  const void* out_proj_b = d_in[4];
  const void* ln1_g      = d_in[5];
  const void* ln1_b      = d_in[6];
  const void* ln2_g      = d_in[7];
  const void* ln2_b      = d_in[8];
  const void* w1         = d_in[9];
  const void* b1         = d_in[10];
  const void* w2         = d_in[11];
  const void* b2         = d_in[12];
  const int*  wptr       = (const int*)d_in[13];

  // Workspace: flag | bf16 weight arena (3 MB) | Q|K|V (3 x 8 MB).
  // After attn: Q holds ctx; K region hosts attn_out then mlp; V region
  // hosts h. a1 lives in d_out (xb dead after QKV GEMM; a1 dead before the
  // final LN2 write).
  char* ws = (char*)d_ws;
  int* flag = (int*)ws;
  bf16* warena = (bf16*)(ws + 256);
  bf16* wq  = warena;
  bf16* wo  = warena + 786432;
  bf16* w1b = warena + 1048576;
  bf16* w2b = warena + 1310720;
  bf16* qkvS = (bf16*)(ws + 256 + 3145728);  // Q|K|V split, 24 MB
  bf16* ctx      = qkvS;                      // attn writes ctx over Q
  bf16* attn_out = qkvS + (size_t)M_ROWS * DMODEL;       // K region
  bf16* h        = qkvS + 2 * (size_t)M_ROWS * DMODEL;   // V region
  bf16* mlp      = attn_out;                  // K region reuse (ln1 done)
  bf16* xb       = (bf16*)d_out;
  bf16* a1       = (bf16*)d_out;

  // 0. convert + self-detect dtype (flag published by block 0)
  cvt_all<<<2816, 256, 0, stream>>>(x, in_proj_w, out_proj_w, w1, w2, xb, warena, flag);
  // 1. Q|K|V = xb @ in_proj_w^T + b   (split outputs), grid 12*64 = 768
  gemm_qkv<<<768, 256, 0, stream>>>(xb, wq, in_proj_b, qkvS, flag);
  // 2. sliding-window attention (QBLK=128, 8 waves); ctx overwrites Q
  attn_fwd<<<512, 512, 0, stream>>>(qkvS, wptr);
  // 3. attn_out = ctx @ wo^T + bo   (64x64 tiles, 1024 blocks = 4/CU)
  gemm_bt<false><<<1024, 256, 0, stream>>>(ctx, wo, out_proj_b, attn_out, flag);
  // 4. h = LN1(x + attn_out)
  ln_fused<true, false><<<dim3(M_ROWS / 4), 256, 0, stream>>>(
      x, attn_out, ln1_g, ln1_b, h, flag);
  // 5. a1 = relu(h @ w1^T + b1)
  gemm_bt<true><<<1024, 256, 0, stream>>>(h, w1b, b1, a1, flag);
  // 6. mlp = a1 @ w2^T + b2
  gemm_bt<false><<<1024, 256, 0, stream>>>(a1, w2b, b2, mlp, flag);
  // 7. out = LN2(h + mlp)
  ln_fused<false, true><<<dim3(M_ROWS / 4), 256, 0, stream>>>(
      h, mlp, ln2_g, ln2_b, d_out, flag);
}

// Round 9
// 198.462 us; speedup vs baseline: 1.0078x; 1.0078x over previous
//
#include <hip/hip_runtime.h>

typedef __bf16 bf16;
typedef __bf16 bf16x2 __attribute__((ext_vector_type(2)));
typedef __bf16 bf16x4 __attribute__((ext_vector_type(4)));
typedef __bf16 bf16x8 __attribute__((ext_vector_type(8)));
typedef float f32x4 __attribute__((ext_vector_type(4)));

#define S_LEN 4096
#define DMODEL 512
#define NHEAD 8
#define DHEAD 64
#define BATCH 2
#define M_ROWS (BATCH * S_LEN)   // 8192
#define K_DIM 512
#define QLD 512                  // per-matrix leading dim after Q|K|V split

// ---------------------------------------------------------------------------
// async global->LDS, 16 B per lane (wave-uniform LDS base + 16*lane scatter).
// ---------------------------------------------------------------------------
__device__ __forceinline__ void async16(void* lds, const void* g) {
  __builtin_amdgcn_global_load_lds(
      (const __attribute__((address_space(1))) unsigned int*)g,
      (__attribute__((address_space(3))) unsigned int*)lds, 16, 0, 0);
}

// ---------------------------------------------------------------------------
// Per-wave dtype detection on x's first 4 KB: 1 if bf16, 0 if f32.
// ---------------------------------------------------------------------------
__device__ __forceinline__ int detect_bf16(const unsigned int* x, int lane) {
  int cnt = 0;
#pragma unroll
  for (int i = 0; i < 16; ++i) {
    const unsigned int w = x[lane * 16 + i];
    const unsigned int e = (w >> 7) & 0xFFu;
    cnt += (e >= 100u && e <= 140u) ? 1 : 0;
  }
#pragma unroll
  for (int off = 1; off < 64; off <<= 1) cnt += __shfl_xor(cnt, off);
  return (cnt >= 700) ? 1 : 0;
}

__device__ __forceinline__ bf16x8 ld8(const void* p, size_t e, bool asF32) {
  if (asF32) {
    const float* q = (const float*)p + e;
    const float4 a = *(const float4*)q;
    const float4 b = *(const float4*)(q + 4);
    bf16x8 r;
    r[0] = (bf16)a.x; r[1] = (bf16)a.y; r[2] = (bf16)a.z; r[3] = (bf16)a.w;
    r[4] = (bf16)b.x; r[5] = (bf16)b.y; r[6] = (bf16)b.z; r[7] = (bf16)b.w;
    return r;
  }
  return *(const bf16x8*)((const bf16*)p + e);
}

__device__ __forceinline__ float ld1(const void* p, size_t e, bool asF32) {
  return asF32 ? ((const float*)p)[e] : (float)((const bf16*)p)[e];
}

// ---------------------------------------------------------------------------
// Conversion kernel. R17: if input is ALREADY bf16, the 2048 x-copy blocks
// early-exit (gemm_qkv reads x directly via flag-selected pointer) -- saves
// the 16 MB xb roundtrip + copy time on the bf16 path. f32 path unchanged.
// Block 0 publishes the flag for downstream kernels.
// ---------------------------------------------------------------------------
__global__ __launch_bounds__(256) void cvt_all(const void* __restrict__ x,
                                               const void* __restrict__ s0,
                                               const void* __restrict__ s1,
                                               const void* __restrict__ s2,
                                               const void* __restrict__ s3,
                                               bf16* __restrict__ xb,
                                               bf16* __restrict__ warena,
                                               int* __restrict__ flag) {
  const int isbf = detect_bf16((const unsigned int*)x, threadIdx.x & 63);
  const bool f32in = (isbf == 0);
  const int b = blockIdx.x;
  if (b == 0 && threadIdx.x == 0) *flag = isbf;
  if (b < 2048) {  // x: 8192*512 = 2048 * 2048 elems
    if (isbf) return;  // bf16 input: downstream reads x directly
    const size_t idx = ((size_t)b * 256 + threadIdx.x) * 8;
    *(bf16x8*)(xb + idx) = ld8(x, idx, f32in);
    return;
  }
  const int wb = b - 2048;
  const void* s;
  size_t doff;
  int lb;
  if (wb < 384)      { s = s0; doff = 0;        lb = wb; }
  else if (wb < 512) { s = s1; doff = 786432;   lb = wb - 384; }
  else if (wb < 640) { s = s2; doff = 1048576;  lb = wb - 512; }
  else               { s = s3; doff = 1310720;  lb = wb - 640; }
  const size_t idx = (size_t)lb * 2048 + threadIdx.x * 8;
  *(bf16x8*)(warena + doff + idx) = ld8(s, idx, f32in);
}

// ---------------------------------------------------------------------------
// QKV GEMM (R2-proven body): qkv = A @ in_proj_w^T + b, [M=8192, N=1536].
// R17: A = (flag ? x : xb) -- bf16 inputs skip the xb staging copy.
// C-write splits into Q|K|V arrays (n>>9 selects; each 8192x512).
// ---------------------------------------------------------------------------
__global__ __launch_bounds__(256) void gemm_qkv(const void* __restrict__ xraw,
                                                const bf16* __restrict__ xb,
                                                const bf16* __restrict__ W,
                                                const void* __restrict__ bias,
                                                bf16* __restrict__ C,
                                                const int* __restrict__ flag) {
  __shared__ __align__(16) bf16 As[128 * 64];
  __shared__ __align__(16) bf16 Ws[128 * 64];

  const bool f32in = (*flag == 0);
  const bf16* A = f32in ? xb : (const bf16*)xraw;
  const int t = threadIdx.x;
  const int lane = t & 63;
  const int wave = t >> 6;
  const int wm = (wave >> 1) * 64;
  const int wn = (wave & 1) * 64;
  const int l16 = lane & 15;
  const int quad = lane >> 4;

  constexpr int NB = 1536 / 128;  // 12 n-blocks per m-band
  const int bid = blockIdx.x;
  const int xcd = bid & 7;
  const int r = bid >> 3;
  const int m0 = (xcd * 8 + r / NB) * 128;
  const int n0 = (r % NB) * 128;

  const int rr = lane >> 3;
  const int cb = (lane & 7) ^ rr;      // XOR swizzle (source side)
  const int sw = l16 & 7;              // read-side swizzle key

  f32x4 acc[4][4];
#pragma unroll
  for (int i = 0; i < 4; ++i)
#pragma unroll
    for (int j = 0; j < 4; ++j) acc[i][j] = (f32x4){0.f, 0.f, 0.f, 0.f};

  for (int kt = 0; kt < K_DIM; kt += 64) {
    __syncthreads();
#pragma unroll
    for (int i = 0; i < 4; ++i) {
      const int r0 = wave * 32 + i * 8;
      async16(&As[r0 * 64], &A[(size_t)(m0 + r0 + rr) * K_DIM + kt + cb * 8]);
    }
#pragma unroll
    for (int i = 0; i < 4; ++i) {
      const int r0 = wave * 32 + i * 8;
      async16(&Ws[r0 * 64], &W[(size_t)(n0 + r0 + rr) * K_DIM + kt + cb * 8]);
    }
    __syncthreads();
#pragma unroll
    for (int ks = 0; ks < 2; ++ks) {
      bf16x8 af[4], wf[4];
#pragma unroll
      for (int mt = 0; mt < 4; ++mt)
        af[mt] = *(const bf16x8*)&As[(wm + mt * 16 + l16) * 64 +
                                     (((ks * 4 + quad) ^ sw) * 8)];
#pragma unroll
      for (int nt = 0; nt < 4; ++nt)
        wf[nt] = *(const bf16x8*)&Ws[(wn + nt * 16 + l16) * 64 +
                                     (((ks * 4 + quad) ^ sw) * 8)];
#pragma unroll
      for (int mt = 0; mt < 4; ++mt)
#pragma unroll
        for (int nt = 0; nt < 4; ++nt)
          acc[mt][nt] = __builtin_amdgcn_mfma_f32_16x16x32_bf16(af[mt], wf[nt],
                                                                acc[mt][nt], 0, 0, 0);
    }
  }

#pragma unroll
  for (int nt = 0; nt < 4; ++nt) {
    const int n = n0 + wn + nt * 16 + l16;        // 0..1535
    const float bv = ld1(bias, n, f32in);
    bf16* Cm = C + (size_t)(n >> 9) * ((size_t)M_ROWS * DMODEL) + (n & 511);
#pragma unroll
    for (int mt = 0; mt < 4; ++mt) {
#pragma unroll
      for (int r4 = 0; r4 < 4; ++r4) {
        const int m = m0 + wm + mt * 16 + quad * 4 + r4;
        Cm[(size_t)m * DMODEL] = (bf16)(acc[mt][nt][r4] + bv);
      }
    }
  }
}

// ---------------------------------------------------------------------------
// Small GEMM (R16): 64x64 tile, grid 1024 = 4 blocks/CU, LDS 32 KB dbuf.
// ---------------------------------------------------------------------------
template <bool RELU>
__global__ __launch_bounds__(256) void gemm_bt(const bf16* __restrict__ A,
                                               const bf16* __restrict__ W,
                                               const void* __restrict__ bias,
                                               bf16* __restrict__ C,
                                               const int* __restrict__ flag) {
  __shared__ __align__(16) bf16 As[2][64 * 64];
  __shared__ __align__(16) bf16 Ws[2][64 * 64];

  const bool f32in = (*flag == 0);
  const int t = threadIdx.x;
  const int lane = t & 63;
  const int wave = t >> 6;        // 0..3
  const int wm = wave * 16;
  const int l16 = lane & 15;
  const int quad = lane >> 4;

  constexpr int NB = 512 / 64;         // 8 n-blocks per m-band
  constexpr int MPX = (M_ROWS / 64) / 8;  // 16 m-bands per XCD
  const int bid = blockIdx.x;          // 0..1023
  const int xcd = bid & 7;
  const int r = bid >> 3;
  const int m0 = (xcd * MPX + r / NB) * 64;
  const int n0 = (r % NB) * 64;

  const int rr = lane >> 3;
  const int cb = (lane & 7) ^ rr;      // XOR swizzle (source side)
  const int sw = l16 & 7;              // read-side swizzle key

  f32x4 acc[4];
#pragma unroll
  for (int j = 0; j < 4; ++j) acc[j] = (f32x4){0.f, 0.f, 0.f, 0.f};

  auto stage = [&](int buf, int kt) {
#pragma unroll
    for (int i = 0; i < 2; ++i) {
      const int r0 = wave * 16 + i * 8;
      async16(&As[buf][r0 * 64],
              &A[(size_t)(m0 + r0 + rr) * K_DIM + kt + cb * 8]);
      async16(&Ws[buf][r0 * 64],
              &W[(size_t)(n0 + r0 + rr) * K_DIM + kt + cb * 8]);
    }
  };

  stage(0, 0);  // prologue
  constexpr int NIT = K_DIM / 64;
  for (int it = 0; it < NIT; ++it) {
    const int cur = it & 1;
    __syncthreads();  // drains tile `it` loads; fences buf[cur^1] reuse
    if (it + 1 < NIT) stage(cur ^ 1, (it + 1) * 64);
#pragma unroll
    for (int ks = 0; ks < 2; ++ks) {
      bf16x8 af, wf[4];
      af = *(const bf16x8*)&As[cur][(wm + l16) * 64 +
                                    (((ks * 4 + quad) ^ sw) * 8)];
#pragma unroll
      for (int nt = 0; nt < 4; ++nt)
        wf[nt] = *(const bf16x8*)&Ws[cur][(nt * 16 + l16) * 64 +
                                          (((ks * 4 + quad) ^ sw) * 8)];
#pragma unroll
      for (int nt = 0; nt < 4; ++nt)
        acc[nt] = __builtin_amdgcn_mfma_f32_16x16x32_bf16(af, wf[nt],
                                                          acc[nt], 0, 0, 0);
    }
  }

#pragma unroll
  for (int nt = 0; nt < 4; ++nt) {
    const int n = n0 + nt * 16 + l16;
    const float bv = ld1(bias, n, f32in);
#pragma unroll
    for (int r4 = 0; r4 < 4; ++r4) {
      const int m = m0 + wm + quad * 4 + r4;
      float v = acc[nt][r4] + bv;
      if (RELU) v = fmaxf(v, 0.f);
      C[(size_t)m * 512 + n] = (bf16)v;
    }
  }
}

// ---------------------------------------------------------------------------
// Sliding-window attention (R15 structure: QBLK=128, 8 waves).
// R17 fix: V prefetch loads (na/nb) are issued BEFORE the next-tile K
// async16. vmcnt retires in issue order, so the V-transpose store at the
// body end previously waited vmcnt(0) -- force-draining the just-issued K
// loads with only ~400 cy of coverage (HBM latency ~900 cy exposed every
// iteration; per-XCD K/V/Q/ctx working set exceeds the 4 MB L2). With V
// loads first, the store waits at vmcnt(1) and K(i+1) stays in flight until
// the next barrier (full-body coverage).
// ---------------------------------------------------------------------------
__global__ __launch_bounds__(512) void attn_fwd(bf16* __restrict__ qkv,
                                                const int* __restrict__ wptr) {
  __shared__ __align__(16) bf16 Kt[2][64 * 64];  // swizzled [key][dh]
  __shared__ __align__(16) bf16 Vt[2][64][72];   // [buf][dh][key] (+8 pad)
  __shared__ __align__(16) bf16 Pbuf[8][16][72]; // per-wave [q][key] (+8 pad)

  const bf16* Q = qkv;
  const bf16* K = qkv + (size_t)M_ROWS * DMODEL;
  const bf16* V = qkv + 2 * (size_t)M_ROWS * DMODEL;
  bf16* ctxw = qkv;  // ctx overwrites Q in place

  const int t = threadIdx.x;       // 0..511
  const int lane = t & 63;
  const int wave = t >> 6;         // 0..7
  const int l16 = lane & 15;
  const int quad = lane >> 4;
  const int rr = lane >> 3;
  const int cb = (lane & 7) ^ rr;   // K staging source swizzle
  const int sw = l16 & 7;           // K read swizzle key

  const int bid = blockIdx.x;               // 0..511
  const int xcd = bid & 7;
  const int jj = bid >> 3;                  // 0..63
  const int pair = xcd * 2 + (jj >> 5);     // 0..15 = (b,h)
  const int qblk = jj & 31;                 // 0..31
  const int h = pair & 7;
  const int b = pair >> 3;
  const int qbase = qblk * 128;
  int window = *wptr;
  if (window < 0) window = 0;
  if (window > S_LEN) window = S_LEN;
  const float sc_log2e = 0.125f * 1.44269504f;  // scale * log2(e)

  const int qrow = qbase + wave * 16 + l16;
  const bf16* qp = Q + (size_t)(b * S_LEN + qrow) * QLD + h * DHEAD;
  const bf16x8 qf0 = *(const bf16x8*)(qp + quad * 8);
  const bf16x8 qf1 = *(const bf16x8*)(qp + 32 + quad * 8);

  f32x4 o[4];
#pragma unroll
  for (int nt = 0; nt < 4; ++nt) o[nt] = (f32x4){0.f, 0.f, 0.f, 0.f};
  float lp[4] = {0.f, 0.f, 0.f, 0.f};

  int kstart = qbase - window;
  if (kstart < 0) kstart = 0;
  kstart &= ~63;
  int kend = qbase + 128 + window;
  if (kend > S_LEN) kend = S_LEN;
  const int niter = (kend - kstart + 63) >> 6;

  // V transpose mapping for 512 threads: 2 keys x 4 dh per thread.
  const int vk = (t & 31) * 2;        // key pair 0..62
  const int vd = (t >> 5) * 4;        // dh group 0..60
  const bf16* vbase = V + (size_t)(b * S_LEN) * QLD + h * DHEAD + vd;
  const bf16* kbase = K + (size_t)(b * S_LEN) * QLD + h * DHEAD;

  // prologue: stage K tile 0 into Kt[0] (1 async16/thread, 8 rows/wave)
  {
    const int r0 = wave * 8;
    async16(&Kt[0][r0 * 64],
            &kbase[(size_t)(kstart + r0 + rr) * QLD + cb * 8]);
  }
  {  // prologue: stage V tile 0 into Vt[0]
    const bf16* p = vbase + (size_t)(kstart + vk) * QLD;
    const bf16x4 va = *(const bf16x4*)p;
    const bf16x4 vb = *(const bf16x4*)(p + QLD);
#pragma unroll
    for (int j = 0; j < 4; ++j) {
      bf16x2 pr; pr[0] = va[j]; pr[1] = vb[j];
      *(bf16x2*)&Vt[0][vd + j][vk] = pr;
    }
  }

  for (int it = 0; it < niter; ++it) {
    const int kt = kstart + it * 64;
    const int cur = it & 1;
    __syncthreads();  // implicit vmcnt(0): Kt[cur] async loads complete

    bf16x4 na, nb;
    const bool have_next = (it + 1 < niter);
    if (have_next) {
      // V loads FIRST (consumed at body end -> vmcnt(1) leaves K in flight)
      const bf16* p = vbase + (size_t)(kt + 64 + vk) * QLD;
      na = *(const bf16x4*)p;
      nb = *(const bf16x4*)(p + QLD);
      // then next-tile K async16 (drains only at next-iter barrier)
      const int r0 = wave * 8;
      async16(&Kt[cur ^ 1][r0 * 64],
              &kbase[(size_t)(kt + 64 + r0 + rr) * QLD + cb * 8]);
    }

    f32x4 s[4];
#pragma unroll
    for (int t4 = 0; t4 < 4; ++t4) s[t4] = (f32x4){0.f, 0.f, 0.f, 0.f};

    __builtin_amdgcn_s_setprio(1);
#pragma unroll
    for (int t4 = 0; t4 < 4; ++t4) {
      const int row = t4 * 16 + l16;
      const bf16x8 k0 = *(const bf16x8*)&Kt[cur][row * 64 + ((quad ^ sw) * 8)];
      const bf16x8 k1 =
          *(const bf16x8*)&Kt[cur][row * 64 + (((4 + quad) ^ sw) * 8)];
      s[t4] = __builtin_amdgcn_mfma_f32_16x16x32_bf16(qf0, k0, s[t4], 0, 0, 0);
      s[t4] = __builtin_amdgcn_mfma_f32_16x16x32_bf16(qf1, k1, s[t4], 0, 0, 0);
    }
    __builtin_amdgcn_s_setprio(0);

#pragma unroll
    for (int r = 0; r < 4; ++r) {
      const int q = qbase + wave * 16 + quad * 4 + r;
      const int lo = q - window, hi = q + window;
#pragma unroll
      for (int t4 = 0; t4 < 4; ++t4) {
        const int key = kt + t4 * 16 + l16;
        const float p = (key >= lo && key <= hi)
                            ? __builtin_amdgcn_exp2f(s[t4][r] * sc_log2e)
                            : 0.f;
        lp[r] += p;
        Pbuf[wave][quad * 4 + r][t4 * 16 + l16] = (bf16)p;
      }
    }

    const bf16x8 pf0 = *(const bf16x8*)&Pbuf[wave][l16][quad * 8];
    const bf16x8 pf1 = *(const bf16x8*)&Pbuf[wave][l16][32 + quad * 8];
    __builtin_amdgcn_s_setprio(1);
#pragma unroll
    for (int nt = 0; nt < 4; ++nt) {
      const bf16x8 v0 = *(const bf16x8*)&Vt[cur][nt * 16 + l16][quad * 8];
      const bf16x8 v1 = *(const bf16x8*)&Vt[cur][nt * 16 + l16][32 + quad * 8];
      o[nt] = __builtin_amdgcn_mfma_f32_16x16x32_bf16(pf0, v0, o[nt], 0, 0, 0);
      o[nt] = __builtin_amdgcn_mfma_f32_16x16x32_bf16(pf1, v1, o[nt], 0, 0, 0);
    }
    __builtin_amdgcn_s_setprio(0);

    if (have_next) {
#pragma unroll
      for (int j = 0; j < 4; ++j) {
        bf16x2 pr; pr[0] = na[j]; pr[1] = nb[j];
        *(bf16x2*)&Vt[cur ^ 1][vd + j][vk] = pr;
      }
    }
  }

#pragma unroll
  for (int r = 0; r < 4; ++r) {
#pragma unroll
    for (int off = 1; off < 16; off <<= 1) lp[r] += __shfl_xor(lp[r], off);
    const float inv = (lp[r] > 0.f) ? (1.0f / lp[r]) : 0.f;
    const int q = qbase + wave * 16 + quad * 4 + r;
#pragma unroll
    for (int nt = 0; nt < 4; ++nt) {
      ctxw[(size_t)(b * S_LEN + q) * QLD + h * DHEAD + nt * 16 + l16] =
          (bf16)(o[nt][r] * inv);
    }
  }
}

// ---------------------------------------------------------------------------
// Fused residual + LayerNorm (R3-verified). One wave per row, 4 rows/block.
// ---------------------------------------------------------------------------
template <bool A_RAW, bool OUT_RAW>
__global__ __launch_bounds__(256) void ln_fused(const void* __restrict__ a,
                                                const bf16* __restrict__ bres,
                                                const void* __restrict__ g,
                                                const void* __restrict__ be,
                                                void* __restrict__ out,
                                                const int* __restrict__ flag) {
  const bool f32in = (*flag == 0);
  const int row = blockIdx.x * 4 + (threadIdx.x >> 6);
  const int lane = threadIdx.x & 63;
  const size_t base = (size_t)row * DMODEL + lane * 8;
  const bf16x8 va = ld8(a, base, A_RAW && f32in);
  const bf16x8 vb = *(const bf16x8*)(bres + base);
  float v[8], s = 0.f, s2 = 0.f;
#pragma unroll
  for (int j = 0; j < 8; ++j) {
    v[j] = (float)va[j] + (float)vb[j];
    s += v[j];
    s2 += v[j] * v[j];
  }
#pragma unroll
  for (int off = 1; off < 64; off <<= 1) {
    s += __shfl_xor(s, off);
    s2 += __shfl_xor(s2, off);
  }
  const float mean = s * (1.0f / DMODEL);
  float var = s2 * (1.0f / DMODEL) - mean * mean;
  if (var < 0.f) var = 0.f;
  const float rstd = rsqrtf(var + 1e-5f);
  const bf16x8 gv = ld8(g, lane * 8, f32in);
  const bf16x8 bev = ld8(be, lane * 8, f32in);
  float ov[8];
#pragma unroll
  for (int j = 0; j < 8; ++j)
    ov[j] = (v[j] - mean) * rstd * (float)gv[j] + (float)bev[j];
  if (OUT_RAW && f32in) {
    float4 o0 = {ov[0], ov[1], ov[2], ov[3]};
    float4 o1 = {ov[4], ov[5], ov[6], ov[7]};
    *(float4*)((float*)out + base) = o0;
    *(float4*)((float*)out + base + 4) = o1;
  } else {
    bf16x8 ob;
#pragma unroll
    for (int j = 0; j < 8; ++j) ob[j] = (bf16)ov[j];
    *(bf16x8*)((bf16*)out + base) = ob;
  }
}

// ---------------------------------------------------------------------------
extern "C" void kernel_launch(void* const* d_in, const int* in_sizes, int n_in,
                              void* d_out, int out_size, void* d_ws, size_t ws_size,
                              hipStream_t stream) {
  const void* x          = d_in[0];
  const void* in_proj_w  = d_in[1];
  const void* in_proj_b  = d_in[2];
  const void* out_proj_w = d_in[3];
  const void* out_proj_b = d_in[4];
  const void* ln1_g      = d_in[5];
  const void* ln1_b      = d_in[6];
  const void* ln2_g      = d_in[7];
  const void* ln2_b      = d_in[8];
  const void* w1         = d_in[9];
  const void* b1         = d_in[10];
  const void* w2         = d_in[11];
  const void* b2         = d_in[12];
  const int*  wptr       = (const int*)d_in[13];

  // Workspace: flag | bf16 weight arena (3 MB) | Q|K|V (3 x 8 MB).
  // After attn: Q holds ctx; K region hosts attn_out then mlp; V region
  // hosts h. a1 lives in d_out (xb dead after QKV GEMM; a1 dead before the
  // final LN2 write).
  char* ws = (char*)d_ws;
  int* flag = (int*)ws;
  bf16* warena = (bf16*)(ws + 256);
  bf16* wq  = warena;
  bf16* wo  = warena + 786432;
  bf16* w1b = warena + 1048576;
  bf16* w2b = warena + 1310720;
  bf16* qkvS = (bf16*)(ws + 256 + 3145728);  // Q|K|V split, 24 MB
  bf16* ctx      = qkvS;                      // attn writes ctx over Q
  bf16* attn_out = qkvS + (size_t)M_ROWS * DMODEL;       // K region
  bf16* h        = qkvS + 2 * (size_t)M_ROWS * DMODEL;   // V region
  bf16* mlp      = attn_out;                  // K region reuse (ln1 done)
  bf16* xb       = (bf16*)d_out;
  bf16* a1       = (bf16*)d_out;

  // 0. convert + self-detect dtype (x-copy skipped when input is bf16)
  cvt_all<<<2816, 256, 0, stream>>>(x, in_proj_w, out_proj_w, w1, w2, xb, warena, flag);
  // 1. Q|K|V = A @ in_proj_w^T + b   (A = x if bf16, else xb), grid 768
  gemm_qkv<<<768, 256, 0, stream>>>(x, xb, wq, in_proj_b, qkvS, flag);
  // 2. sliding-window attention (QBLK=128, 8 waves); ctx overwrites Q
  attn_fwd<<<512, 512, 0, stream>>>(qkvS, wptr);
  // 3. attn_out = ctx @ wo^T + bo   (64x64 tiles, 1024 blocks = 4/CU)
  gemm_bt<false><<<1024, 256, 0, stream>>>(ctx, wo, out_proj_b, attn_out, flag);
  // 4. h = LN1(x + attn_out)
  ln_fused<true, false><<<dim3(M_ROWS / 4), 256, 0, stream>>>(
      x, attn_out, ln1_g, ln1_b, h, flag);
  // 5. a1 = relu(h @ w1^T + b1)
  gemm_bt<true><<<1024, 256, 0, stream>>>(h, w1b, b1, a1, flag);
  // 6. mlp = a1 @ w2^T + b2
  gemm_bt<false><<<1024, 256, 0, stream>>>(a1, w2b, b2, mlp, flag);
  // 7. out = LN2(h + mlp)
  ln_fused<false, true><<<dim3(M_ROWS / 4), 256, 0, stream>>>(
      h, mlp, ln2_g, ln2_b, d_out, flag);
}